// Round 2
// baseline (467.342 us; speedup 1.0000x reference)
//
#include <hip/hip_runtime.h>

#define VQ_N 131072   // rows = 32*64*64
#define VQ_D 64
#define VQ_K 512

// ws float layout:
//   [64 .. 64+512)        half codebook norms  0.5*||e_k||^2
//   [576 .. 576+32768)    transposed codebook cbt[K][D]
// loss accumulator lives in d_out[VQ_N*VQ_D] (zeroed by prep each launch).

__global__ __launch_bounds__(512) void vq_prep(const float* __restrict__ enc,
                                               float* __restrict__ ws,
                                               float* loss_acc) {
    int k = threadIdx.x;          // 0..511
    if (k == 0) loss_acc[0] = 0.0f;
    float* cbt = ws + 576;
    float hn = 0.0f;
    #pragma unroll 8
    for (int d = 0; d < VQ_D; ++d) {
        float v = enc[d * VQ_K + k];   // enc is [D][K] row-major
        cbt[k * VQ_D + d] = v;
        hn = fmaf(v, v, hn);
    }
    ws[64 + k] = 0.5f * hn;
}

// Exact-enough squared distance in fp64 (fp32*fp32 products are exact in f64).
__device__ double dist_f64(const float* __restrict__ xv, const float* __restrict__ e) {
    double acc = 0.0;
    #pragma unroll
    for (int d = 0; d < VQ_D; ++d) {
        double diff = (double)xv[d] - (double)e[d];
        acc = fma(diff, diff, acc);
    }
    return acc;
}

__global__ __launch_bounds__(256) void vq_main(const float* __restrict__ x,
                                               const float* __restrict__ ws,
                                               float* __restrict__ out,
                                               float* loss_acc) {
    const float* __restrict__ hnorm = ws + 64;
    const float* __restrict__ cbt   = ws + 576;

    const int row = blockIdx.x * blockDim.x + threadIdx.x;

    // Load this thread's row of x into registers (16 x float4).
    float xv[VQ_D];
    const float4* xr = reinterpret_cast<const float4*>(x + (size_t)row * VQ_D);
    #pragma unroll
    for (int j = 0; j < VQ_D / 4; ++j) {
        float4 v = xr[j];
        xv[4*j+0] = v.x; xv[4*j+1] = v.y; xv[4*j+2] = v.z; xv[4*j+3] = v.w;
    }

    // fp32 screening pass: track top-2 candidates (strict < keeps first-occurrence).
    float best1 = 3.4e38f, best2 = 3.4e38f;
    int   i1 = 0,          i2 = 0;
    for (int k = 0; k < VQ_K; ++k) {
        // Wave-uniform codebook loads -> scalar loads, off the VALU critical path.
        const float4* e = reinterpret_cast<const float4*>(cbt + k * VQ_D);
        float a0 = 0.f, a1 = 0.f, a2 = 0.f, a3 = 0.f;
        #pragma unroll
        for (int j = 0; j < VQ_D / 4; ++j) {
            float4 v = e[j];
            a0 = fmaf(xv[4*j+0], v.x, a0);
            a1 = fmaf(xv[4*j+1], v.y, a1);
            a2 = fmaf(xv[4*j+2], v.z, a2);
            a3 = fmaf(xv[4*j+3], v.w, a3);
        }
        // s_k = 0.5*||e_k||^2 - x.e_k  (same argmin as full squared distance)
        float s = hnorm[k] - ((a0 + a1) + (a2 + a3));
        if (s < best1) { best2 = best1; i2 = i1; best1 = s; i1 = k; }
        else if (s < best2) { best2 = s; i2 = k; }
    }

    // fp64 rescreen of the two finalists: decides near-ties exactly,
    // matching the float64 numpy reference's argmin.
    double d1 = dist_f64(xv, cbt + i1 * VQ_D);
    double d2 = dist_f64(xv, cbt + i2 * VQ_D);
    int bidx;
    if (d1 < d2)      bidx = i1;
    else if (d2 < d1) bidx = i2;
    else              bidx = (i1 < i2) ? i1 : i2;   // exact tie: first occurrence

    // Epilogue: gather winning codeword, write output, accumulate loss.
    const float4* q4 = reinterpret_cast<const float4*>(cbt + bidx * VQ_D);
    float4* o4 = reinterpret_cast<float4*>(out + (size_t)row * VQ_D);
    float lsum = 0.0f;
    #pragma unroll
    for (int j = 0; j < VQ_D / 4; ++j) {
        float4 v = q4[j];
        o4[j] = v;
        float d0 = v.x - xv[4*j+0];
        float e1 = v.y - xv[4*j+1];
        float e2 = v.z - xv[4*j+2];
        float e3 = v.w - xv[4*j+3];
        lsum = fmaf(d0, d0, lsum);
        lsum = fmaf(e1, e1, lsum);
        lsum = fmaf(e2, e2, lsum);
        lsum = fmaf(e3, e3, lsum);
    }
    // 64-lane wave reduction, one atomic per wave.
    #pragma unroll
    for (int off = 32; off > 0; off >>= 1)
        lsum += __shfl_xor(lsum, off, 64);
    if ((threadIdx.x & 63) == 0)
        atomicAdd(loss_acc, lsum);
}

__global__ void vq_finalize(float* loss_acc) {
    // loss = (BETA + 1) * mean((q-x)^2), BETA = 0.25
    loss_acc[0] = 1.25f * loss_acc[0] / (float)(VQ_N * VQ_D);
}

extern "C" void kernel_launch(void* const* d_in, const int* in_sizes, int n_in,
                              void* d_out, int out_size, void* d_ws, size_t ws_size,
                              hipStream_t stream) {
    const float* x   = (const float*)d_in[0];   // (32,64,64,64) fp32
    const float* enc = (const float*)d_in[1];   // (64,512) fp32
    float* out = (float*)d_out;                 // 8388608 quantised + 1 loss
    float* ws  = (float*)d_ws;
    float* loss_acc = out + (size_t)VQ_N * VQ_D;

    vq_prep<<<1, 512, 0, stream>>>(enc, ws, loss_acc);
    vq_main<<<VQ_N / 256, 256, 0, stream>>>(x, ws, out, loss_acc);
    vq_finalize<<<1, 1, 0, stream>>>(loss_acc);
}